// Round 3
// baseline (289.212 us; speedup 1.0000x reference)
//
#include <hip/hip_runtime.h>
#include <hip/hip_bf16.h>
#include <math.h>

constexpr int H    = 256;
constexpr int KNB  = 32;
constexpr int TPB  = 512;
constexpr int TLOC = 8;   // per-thread local candidates (per-wave top-32 safety: P(overflow) ~ 1e-9)

__device__ __forceinline__ float gelu_fast(float x) {
    // gelu_tanh(x) = x * sigmoid(2u), u = 0.79788456(x + 0.044715 x^3)
    float u = 0.7978845608028654f * (x + 0.044715f * x * x * x);
    float t = exp2f(-2.885390081777927f * u);   // e^{-2u}
    return x / (1.0f + t);
}

__global__ __launch_bounds__(TPB, 6)
void supernode_fused(const float* __restrict__ pos, int N,
                     const int* __restrict__ supidx,
                     const float* __restrict__ W1, const float* __restrict__ b1,
                     const float* __restrict__ W2, const float* __restrict__ b2,
                     const float* __restrict__ Wp, const float* __restrict__ bp,
                     float* __restrict__ out)
{
    __shared__ float smem[H * KNB];   // 32 KB multipurpose: cand / mt / pk / matvec partials
    __shared__ float rf[KNB][5];      // rel features, stride 5 (conflict-free)
    __shared__ int   sel[KNB];
    __shared__ float hb[H];
    __shared__ float feats[2 * H];

    const int s    = blockIdx.x;
    const int t    = threadIdx.x;
    const int lane = t & 63;
    const int w    = t >> 6;          // wave id 0..7

    const int sidx = supidx[s];
    const float sx = pos[3 * sidx + 0];
    const float sy = pos[3 * sidx + 1];
    const float sz = pos[3 * sidx + 2];

    constexpr float L2_10000 = 13.287712379549449f;

    // ---------- phase 0: supernode abs-pos embed -> feats[0..255] (early, off critical tail)
    if (t < H) {
        float se = 0.f;
        if (t < 252) {
            int c  = t / 84;
            int rr = t - c * 84;
            int f  = (rr < 42) ? rr : rr - 42;
            float coord = (c == 0) ? sx : ((c == 1) ? sy : sz);
            float ang = coord * exp2f(-(float)f * (L2_10000 / 42.f));
            se = (rr < 42) ? __sinf(ang) : __cosf(ang);
        }
        feats[t] = se;
    }

    // ---------- phase 1: kNN scan, per-thread top-8 ----------
    float ld[TLOC];
    int   li[TLOC];
#pragma unroll
    for (int j = 0; j < TLOC; j++) { ld[j] = INFINITY; li[j] = 0x7fffffff; }
    float worst = INFINITY;
    int   wslot = 0;

    auto upd = [&](float d2, int i) {
        if (d2 < worst) {
#pragma unroll
            for (int j = 0; j < TLOC; j++) if (j == wslot) { ld[j] = d2; li[j] = i; }
            worst = ld[0]; wslot = 0;
#pragma unroll
            for (int j = 1; j < TLOC; j++) if (ld[j] > worst) { worst = ld[j]; wslot = j; }
        }
    };

    int base = 0;
    for (; base + 4 * TPB <= N; base += 4 * TPB) {
        const int i0 = base + t, i1 = i0 + TPB, i2 = i1 + TPB, i3 = i2 + TPB;
        float x0 = pos[3 * i0], y0 = pos[3 * i0 + 1], z0 = pos[3 * i0 + 2];
        float x1 = pos[3 * i1], y1 = pos[3 * i1 + 1], z1 = pos[3 * i1 + 2];
        float x2 = pos[3 * i2], y2 = pos[3 * i2 + 1], z2 = pos[3 * i2 + 2];
        float x3 = pos[3 * i3], y3 = pos[3 * i3 + 1], z3 = pos[3 * i3 + 2];
        float dx, dy, dz;
        dx = sx - x0; dy = sy - y0; dz = sz - z0; float d20 = dx*dx + dy*dy + dz*dz;
        dx = sx - x1; dy = sy - y1; dz = sz - z1; float d21 = dx*dx + dy*dy + dz*dz;
        dx = sx - x2; dy = sy - y2; dz = sz - z2; float d22 = dx*dx + dy*dy + dz*dz;
        dx = sx - x3; dy = sy - y3; dz = sz - z3; float d23 = dx*dx + dy*dy + dz*dz;
        upd(d20, i0); upd(d21, i1); upd(d22, i2); upd(d23, i3);
    }
    for (int i = base + t; i < N; i += TPB) {
        float px = pos[3 * i], py = pos[3 * i + 1], pz = pos[3 * i + 2];
        float dx = sx - px, dy = sy - py, dz = sz - pz;
        upd(dx*dx + dy*dy + dz*dz, i);
    }

    // ---------- phase 2: wave-local top-32 extraction (no barriers) ----------
    // candidates: smem[0..255] = d2, (int*)smem[256..511] = idx
    float* candd = smem;
    int*   candi = (int*)(smem + 256);
    for (int r = 0; r < KNB; r++) {
        float v = INFINITY; int gi = 0x7fffffff;
#pragma unroll
        for (int j = 0; j < TLOC; j++) {
            bool b = (ld[j] < v) || (ld[j] == v && li[j] < gi);
            if (b) { v = ld[j]; gi = li[j]; }
        }
#pragma unroll
        for (int off = 32; off; off >>= 1) {
            float ov = __shfl_xor(v, off);
            int   oi = __shfl_xor(gi, off);
            if (ov < v || (ov == v && oi < gi)) { v = ov; gi = oi; }
        }
        if (lane == 0) { candd[w * KNB + r] = v; candi[w * KNB + r] = gi; }
#pragma unroll
        for (int j = 0; j < TLOC; j++) if (li[j] == gi) { ld[j] = INFINITY; li[j] = 0x7fffffff; }
    }
    __syncthreads();

    // ---------- phase 3: rank-merge 256 candidates -> global top-32 ----------
    if (t < 256) {
        float my  = candd[t];
        int   myi = candi[t];
        int rank = 0;
        for (int u = 0; u < 256; u += 4) {
            float4 d4 = *(const float4*)&candd[u];
            int4   i4 = *(const int4*)&candi[u];
            rank += (d4.x < my) || (d4.x == my && i4.x < myi);
            rank += (d4.y < my) || (d4.y == my && i4.y < myi);
            rank += (d4.z < my) || (d4.z == my && i4.z < myi);
            rank += (d4.w < my) || (d4.w == my && i4.w < myi);
        }
        if (rank < KNB) sel[rank] = myi;
    }
    __syncthreads();

    // ---------- phase 4: rel features ----------
    if (t < KNB) {
        int ni = sel[t];
        float px = pos[3 * ni], py = pos[3 * ni + 1], pz = pos[3 * ni + 2];
        float rx = sx - px, ry = sy - py, rz = sz - pz;
        float dd = sqrtf(rx * rx + ry * ry + rz * rz);
        rf[t][0] = rx; rf[t][1] = ry; rf[t][2] = rz; rf[t][3] = dd;
    }
    __syncthreads();

    // ---------- phase 5: sincos embed -> mt[i=256][k=32] in smem ----------
#pragma unroll
    for (int n = 0; n < 8; n++) {
        int item = t + n * TPB;
        int k  = item & 31;
        int cf = item >> 5;          // 0..127
        int c  = cf >> 5;
        int f  = cf & 31;
        float ang = rf[k][c] * exp2f(-(float)f * (L2_10000 / 32.f));
        smem[(c * 64 + f) * KNB + k]      = __sinf(ang);
        smem[(c * 64 + 32 + f) * KNB + k] = __cosf(ang);
    }
    __syncthreads();

    // ---------- phase 6: GEMM1 h = gelu(msg_in @ W1 + b1), k-partial sums ----------
    const int jg = t & 31, kg = t >> 5;   // kg 0..15
    const int j0 = jg * 8, k0 = kg * 2;

    float acc[2][8];
#pragma unroll
    for (int jj = 0; jj < 8; jj++) {
        float bv = b1[j0 + jj];
        acc[0][jj] = bv; acc[1][jj] = bv;
    }

#pragma unroll 4
    for (int i = 0; i < H; i++) {
        float2 a = *(const float2*)&smem[i * KNB + k0];
        const float* wr = W1 + i * H + j0;
        float4 w0 = *(const float4*)wr;
        float4 w1 = *(const float4*)(wr + 4);
        float wv8[8] = { w0.x, w0.y, w0.z, w0.w, w1.x, w1.y, w1.z, w1.w };
#pragma unroll
        for (int jj = 0; jj < 8; jj++) {
            acc[0][jj] += a.x * wv8[jj];
            acc[1][jj] += a.y * wv8[jj];
        }
    }
    __syncthreads();   // mt reads done; smem becomes pk[16][256]

    {
        float g4[8];
#pragma unroll
        for (int jj = 0; jj < 8; jj++)
            g4[jj] = gelu_fast(acc[0][jj]) + gelu_fast(acc[1][jj]);
        float4 v0 = { g4[0], g4[1], g4[2], g4[3] };
        float4 v1 = { g4[4], g4[5], g4[6], g4[7] };
        *(float4*)&smem[kg * H + j0]     = v0;
        *(float4*)&smem[kg * H + j0 + 4] = v1;
    }
    __syncthreads();

    if (t < H) {
        float hbv = 0.f;
#pragma unroll
        for (int g = 0; g < 16; g++) hbv += smem[g * H + t];
        hb[t] = hbv * (1.0f / 32.0f);
    }
    __syncthreads();

    // ---------- phase 7: GEMM2 matvec agg = hb @ W2 + b2 (2 threads/output) ----------
    {
        const int j = t & 255, half = t >> 8;
        const int i0 = half * 128;
        float a[8];
#pragma unroll
        for (int u = 0; u < 8; u++) a[u] = 0.f;
        for (int st = 0; st < 16; st++) {
            int i = i0 + st * 8;
#pragma unroll
            for (int u = 0; u < 8; u++)
                a[u] += hb[i + u] * W2[(i + u) * H + j];
        }
        smem[t] = ((a[0] + a[1]) + (a[2] + a[3])) + ((a[4] + a[5]) + (a[6] + a[7]));
    }
    __syncthreads();
    if (t < 256) feats[H + t] = smem[t] + smem[256 + t] + b2[t];
    __syncthreads();

    // ---------- phase 8: final projection out = feats @ Wp + bp (2 threads/output) ----------
    {
        const int j = t & 255, half = t >> 8;
        const int i0 = half * 256;
        float o[8];
#pragma unroll
        for (int u = 0; u < 8; u++) o[u] = 0.f;
        for (int st = 0; st < 32; st++) {
            int i = i0 + st * 8;
#pragma unroll
            for (int u = 0; u < 8; u++)
                o[u] += feats[i + u] * Wp[(i + u) * H + j];
        }
        smem[512 + t] = ((o[0] + o[1]) + (o[2] + o[3])) + ((o[4] + o[5]) + (o[6] + o[7]));
    }
    __syncthreads();
    if (t < 256) out[s * H + t] = smem[512 + t] + smem[768 + t] + bp[t];
}

extern "C" void kernel_launch(void* const* d_in, const int* in_sizes, int n_in,
                              void* d_out, int out_size, void* d_ws, size_t ws_size,
                              hipStream_t stream) {
    const float* pos = (const float*)d_in[0];
    const int*   sup = (const int*)d_in[1];
    const float* W1  = (const float*)d_in[2];
    const float* b1  = (const float*)d_in[3];
    const float* W2  = (const float*)d_in[4];
    const float* b2  = (const float*)d_in[5];
    const float* Wp  = (const float*)d_in[6];
    const float* bp  = (const float*)d_in[7];

    const int N = in_sizes[0] / 3;
    const int S = in_sizes[1];
    float* out = (float*)d_out;

    supernode_fused<<<S, TPB, 0, stream>>>(pos, N, sup, W1, b1, W2, b2, Wp, bp, out);
}

// Round 4
// 191.733 us; speedup vs baseline: 1.5084x; 1.5084x over previous
//
#include <hip/hip_runtime.h>
#include <hip/hip_bf16.h>
#include <math.h>

typedef short bf16x8 __attribute__((ext_vector_type(8)));
typedef float f32x4  __attribute__((ext_vector_type(4)));

constexpr int H    = 256;
constexpr int KNB  = 32;
constexpr int TPB  = 512;
constexpr int TLOC = 8;

__device__ __forceinline__ ushort f2bf(float x) {
    unsigned u = __float_as_uint(x);
    u += 0x7FFF + ((u >> 16) & 1);      // round-to-nearest-even
    return (ushort)(u >> 16);
}

__device__ __forceinline__ float gelu_fast(float x) {
    // gelu_tanh(x) = x * sigmoid(2u), u = 0.79788456(x + 0.044715 x^3)
    float u = 0.7978845608028654f * (x + 0.044715f * x * x * x);
    float t = exp2f(-2.885390081777927f * u);   // e^{-2u}
    return x / (1.0f + t);
}

// ---- prep: W1t[j][i] = bf16(W1[i][j]), via LDS-tiled transpose ----
__global__ __launch_bounds__(256)
void prep_w1t(const float* __restrict__ W1, ushort* __restrict__ W1t) {
    __shared__ float tile[32][33];
    const int b  = blockIdx.x;          // 64 blocks = 8x8 tiles of 32x32
    const int ti = b >> 3, tj = b & 7;
    const int r  = threadIdx.x >> 5, c = threadIdx.x & 31;
#pragma unroll
    for (int rr = r; rr < 32; rr += 8)
        tile[rr][c] = W1[(ti * 32 + rr) * H + tj * 32 + c];
    __syncthreads();
#pragma unroll
    for (int rr = r; rr < 32; rr += 8) {
        int j = tj * 32 + rr;
        W1t[j * H + ti * 32 + c] = f2bf(tile[c][rr]);
    }
}

__global__ __launch_bounds__(TPB, 4)
void supernode_fused(const float* __restrict__ pos, int N,
                     const int* __restrict__ supidx,
                     const ushort* __restrict__ W1t, const float* __restrict__ b1,
                     const float* __restrict__ W2, const float* __restrict__ b2,
                     const float* __restrict__ Wp, const float* __restrict__ bp,
                     float* __restrict__ out)
{
    __shared__ ushort msg[KNB * H];   // 16 KB bf16 msg[k][i], XOR-swizzled rows
    __shared__ float  candd[256];
    __shared__ int    candi[256];
    __shared__ float  rf[KNB][5];
    __shared__ int    sel[KNB];
    __shared__ float  hb[H];
    __shared__ float  feats[2 * H];
    __shared__ float  p2[512];

    const int s    = blockIdx.x;
    const int t    = threadIdx.x;
    const int lane = t & 63;
    const int w    = t >> 6;            // wave 0..7

    const int sidx = supidx[s];
    const float sx = pos[3 * sidx + 0];
    const float sy = pos[3 * sidx + 1];
    const float sz = pos[3 * sidx + 2];

    constexpr float L2_10000 = 13.287712379549449f;

    // ---- phase 0: supernode abs-pos embed -> feats[0..255]
    if (t < H) {
        float se = 0.f;
        if (t < 252) {
            int c  = t / 84;
            int rr = t - c * 84;
            int f  = (rr < 42) ? rr : rr - 42;
            float coord = (c == 0) ? sx : ((c == 1) ? sy : sz);
            float ang = coord * exp2f(-(float)f * (L2_10000 / 42.f));
            se = (rr < 42) ? __sinf(ang) : __cosf(ang);
        }
        feats[t] = se;
    }

    // ---- phase 1: kNN scan, per-thread top-8, float4 loads ----
    float ld[TLOC];
    int   li[TLOC];
#pragma unroll
    for (int j = 0; j < TLOC; j++) { ld[j] = INFINITY; li[j] = 0x7fffffff; }
    float worst = INFINITY;
    int   wslot = 0;

    auto upd = [&](float px, float py, float pz, int i) {
        float dx = sx - px, dy = sy - py, dz = sz - pz;
        float d2 = dx * dx + dy * dy + dz * dz;
        if (d2 < worst) {
#pragma unroll
            for (int j = 0; j < TLOC; j++) if (j == wslot) { ld[j] = d2; li[j] = i; }
            worst = ld[0]; wslot = 0;
#pragma unroll
            for (int j = 1; j < TLOC; j++) if (ld[j] > worst) { worst = ld[j]; wslot = j; }
        }
    };

    int base = 0;
    for (; base + 4 * TPB <= N; base += 4 * TPB) {
        const float4* p4 = (const float4*)(pos + (size_t)base * 3);
        float4 f0 = p4[3 * t + 0];
        float4 f1 = p4[3 * t + 1];
        float4 f2 = p4[3 * t + 2];
        const int ib = base + 4 * t;
        upd(f0.x, f0.y, f0.z, ib + 0);
        upd(f0.w, f1.x, f1.y, ib + 1);
        upd(f1.z, f1.w, f2.x, ib + 2);
        upd(f2.y, f2.z, f2.w, ib + 3);
    }
    for (int i = base + t; i < N; i += TPB)
        upd(pos[3 * i], pos[3 * i + 1], pos[3 * i + 2], i);

    // ---- phase 2: wave-local top-32 extraction (no barriers) ----
    for (int r = 0; r < KNB; r++) {
        float v = INFINITY; int gi = 0x7fffffff;
#pragma unroll
        for (int j = 0; j < TLOC; j++) {
            bool b = (ld[j] < v) || (ld[j] == v && li[j] < gi);
            if (b) { v = ld[j]; gi = li[j]; }
        }
#pragma unroll
        for (int off = 32; off; off >>= 1) {
            float ov = __shfl_xor(v, off);
            int   oi = __shfl_xor(gi, off);
            if (ov < v || (ov == v && oi < gi)) { v = ov; gi = oi; }
        }
        if (lane == 0) { candd[w * KNB + r] = v; candi[w * KNB + r] = gi; }
#pragma unroll
        for (int j = 0; j < TLOC; j++) if (li[j] == gi) { ld[j] = INFINITY; li[j] = 0x7fffffff; }
    }
    __syncthreads();

    // ---- phase 3: rank-merge 256 candidates -> top-32 ----
    if (t < 256) {
        float my  = candd[t];
        int   myi = candi[t];
        int rank = 0;
        for (int u = 0; u < 256; u += 4) {
            float4 d4 = *(const float4*)&candd[u];
            int4   i4 = *(const int4*)&candi[u];
            rank += (d4.x < my) || (d4.x == my && i4.x < myi);
            rank += (d4.y < my) || (d4.y == my && i4.y < myi);
            rank += (d4.z < my) || (d4.z == my && i4.z < myi);
            rank += (d4.w < my) || (d4.w == my && i4.w < myi);
        }
        if (rank < KNB) sel[rank] = myi;
    }
    __syncthreads();

    // ---- phase 4: rel features ----
    if (t < KNB) {
        int ni = sel[t];
        float px = pos[3 * ni], py = pos[3 * ni + 1], pz = pos[3 * ni + 2];
        float rx = sx - px, ry = sy - py, rz = sz - pz;
        float dd = sqrtf(rx * rx + ry * ry + rz * rz);
        rf[t][0] = rx; rf[t][1] = ry; rf[t][2] = rz; rf[t][3] = dd;
    }
    __syncthreads();

    // ---- phase 5: sincos embed -> msg[k][i] bf16, row-XOR swizzle ----
    // elem index = (k<<8 | i) ^ ((k&7)<<3)  (involution, applied on read too)
#pragma unroll
    for (int n = 0; n < 8; n++) {
        int item = t + n * TPB;
        int f = item & 31;
        int c = (item >> 5) & 3;
        int k = item >> 7;
        float ang = rf[k][c] * exp2f(-(float)f * (L2_10000 / 32.f));
        int swz = (k & 7) << 3;
        msg[((k << 8) | (c * 64 + f))      ^ swz] = f2bf(__sinf(ang));
        msg[((k << 8) | (c * 64 + 32 + f)) ^ swz] = f2bf(__cosf(ang));
    }
    __syncthreads();

    // ---- phase 6: MFMA GEMM1  h[j][k] = sum_i W1t[j][i]*msg[k][i] ----
    // wave w owns j-rows [32w, 32w+32): M-tiles {2w, 2w+1}, N-tiles {0,1}
    {
        const int lr = lane & 15;       // A-row / B-col within tile
        const int lg = lane >> 4;       // k-group 0..3
        f32x4 acc00 = {0,0,0,0}, acc01 = {0,0,0,0};
        f32x4 acc10 = {0,0,0,0}, acc11 = {0,0,0,0};
#pragma unroll
        for (int kk = 0; kk < 8; kk++) {
            const int i0 = kk * 32 + lg * 8;
            bf16x8 a0 = *(const bf16x8*)(W1t + ((32 * w      + lr) << 8) + i0);
            bf16x8 a1 = *(const bf16x8*)(W1t + ((32 * w + 16 + lr) << 8) + i0);
            const int swz = (lr & 7) << 3;
            bf16x8 b0 = *(const bf16x8*)(msg + ((( lr       << 8) | i0) ^ swz));
            bf16x8 b1 = *(const bf16x8*)(msg + ((((lr + 16) << 8) | i0) ^ swz));
            acc00 = __builtin_amdgcn_mfma_f32_16x16x32_bf16(a0, b0, acc00, 0, 0, 0);
            acc01 = __builtin_amdgcn_mfma_f32_16x16x32_bf16(a0, b1, acc01, 0, 0, 0);
            acc10 = __builtin_amdgcn_mfma_f32_16x16x32_bf16(a1, b0, acc10, 0, 0, 0);
            acc11 = __builtin_amdgcn_mfma_f32_16x16x32_bf16(a1, b1, acc11, 0, 0, 0);
        }
        // epilogue: +b1, gelu, sum over 32 neighbors, mean -> hb[j]
        float part[8];
#pragma unroll
        for (int m = 0; m < 2; m++)
#pragma unroll
            for (int r = 0; r < 4; r++) {
                int j = 32 * w + 16 * m + 4 * lg + r;
                float bj = b1[j];
                float h0 = (m == 0 ? acc00[r] : acc10[r]) + bj;
                float h1 = (m == 0 ? acc01[r] : acc11[r]) + bj;
                part[m * 4 + r] = gelu_fast(h0) + gelu_fast(h1);
            }
#pragma unroll
        for (int off = 1; off < 16; off <<= 1)
#pragma unroll
            for (int u = 0; u < 8; u++)
                part[u] += __shfl_xor(part[u], off);
        if (lr == 0) {
#pragma unroll
            for (int u = 0; u < 8; u++) {
                int m = u >> 2, r = u & 3;
                hb[32 * w + 16 * m + 4 * lg + r] = part[u] * (1.0f / 32.0f);
            }
        }
    }
    __syncthreads();

    // ---- phase 7: GEMM2 matvec agg = hb @ W2 + b2 (2 threads/output) ----
    {
        const int j = t & 255, half = t >> 8;
        const int i0 = half * 128;
        float a[8];
#pragma unroll
        for (int u = 0; u < 8; u++) a[u] = 0.f;
        for (int st = 0; st < 16; st++) {
            int i = i0 + st * 8;
#pragma unroll
            for (int u = 0; u < 8; u++)
                a[u] += hb[i + u] * W2[(i + u) * H + j];
        }
        p2[t] = ((a[0] + a[1]) + (a[2] + a[3])) + ((a[4] + a[5]) + (a[6] + a[7]));
    }
    __syncthreads();
    if (t < 256) feats[H + t] = p2[t] + p2[256 + t] + b2[t];
    __syncthreads();

    // ---- phase 8: final projection out = feats @ Wp + bp (2 threads/output) ----
    {
        const int j = t & 255, half = t >> 8;
        const int i0 = half * 256;
        float o[8];
#pragma unroll
        for (int u = 0; u < 8; u++) o[u] = 0.f;
        for (int st = 0; st < 32; st++) {
            int i = i0 + st * 8;
#pragma unroll
            for (int u = 0; u < 8; u++)
                o[u] += feats[i + u] * Wp[(i + u) * H + j];
        }
        p2[t] = ((o[0] + o[1]) + (o[2] + o[3])) + ((o[4] + o[5]) + (o[6] + o[7]));
    }
    __syncthreads();
    if (t < 256) out[s * H + t] = p2[t] + p2[256 + t] + bp[t];
}

extern "C" void kernel_launch(void* const* d_in, const int* in_sizes, int n_in,
                              void* d_out, int out_size, void* d_ws, size_t ws_size,
                              hipStream_t stream) {
    const float* pos = (const float*)d_in[0];
    const int*   sup = (const int*)d_in[1];
    const float* W1  = (const float*)d_in[2];
    const float* b1  = (const float*)d_in[3];
    const float* W2  = (const float*)d_in[4];
    const float* b2  = (const float*)d_in[5];
    const float* Wp  = (const float*)d_in[6];
    const float* bp  = (const float*)d_in[7];

    const int N = in_sizes[0] / 3;
    const int S = in_sizes[1];
    float* out = (float*)d_out;

    ushort* W1t = (ushort*)d_ws;    // 128 KB bf16 W1 transposed

    prep_w1t<<<64, 256, 0, stream>>>(W1, W1t);
    supernode_fused<<<S, TPB, 0, stream>>>(pos, N, sup, W1t, b1, W2, b2, Wp, bp, out);
}

// Round 5
// 102.584 us; speedup vs baseline: 2.8193x; 1.8690x over previous
//
#include <hip/hip_runtime.h>
#include <hip/hip_bf16.h>
#include <math.h>

typedef short bf16x8 __attribute__((ext_vector_type(8)));
typedef float f32x4  __attribute__((ext_vector_type(4)));

constexpr int H    = 256;
constexpr int KNB  = 32;
constexpr int TPB  = 512;
constexpr int CAP  = 1536;   // survivor buffer (expected ~200)

__device__ __forceinline__ ushort f2bf(float x) {
    unsigned u = __float_as_uint(x);
    u += 0x7FFF + ((u >> 16) & 1);      // round-to-nearest-even
    return (ushort)(u >> 16);
}

__device__ __forceinline__ float gelu_fast(float x) {
    float u = 0.7978845608028654f * (x + 0.044715f * x * x * x);
    float t = exp2f(-2.885390081777927f * u);   // e^{-2u}
    return x / (1.0f + t);
}

// ---- prep: W1t[j][i] = bf16(W1[i][j]) (blocks 0..63); pos4 = (x,y,z,|p|^2) ----
__global__ __launch_bounds__(256)
void prep(const float* __restrict__ W1, const float* __restrict__ pos, int N,
          ushort* __restrict__ W1t, float4* __restrict__ pos4) {
    const int b = blockIdx.x;
    if (b < 64) {
        __shared__ float tile[32][33];
        const int ti = b >> 3, tj = b & 7;
        const int r  = threadIdx.x >> 5, c = threadIdx.x & 31;
#pragma unroll
        for (int rr = r; rr < 32; rr += 8)
            tile[rr][c] = W1[(ti * 32 + rr) * H + tj * 32 + c];
        __syncthreads();
#pragma unroll
        for (int rr = r; rr < 32; rr += 8) {
            int j = tj * 32 + rr;
            W1t[j * H + ti * 32 + c] = f2bf(tile[c][rr]);
        }
    } else {
        int i = (b - 64) * 256 + threadIdx.x;
        if (i < N) {
            float x = pos[3 * i], y = pos[3 * i + 1], z = pos[3 * i + 2];
            pos4[i] = make_float4(x, y, z, fmaf(x, x, fmaf(y, y, z * z)));
        }
    }
}

__global__ __launch_bounds__(TPB, 4)
void supernode_fused(const float4* __restrict__ pos4, int N,
                     const int* __restrict__ supidx,
                     const ushort* __restrict__ W1t, const float* __restrict__ b1,
                     const float* __restrict__ W2, const float* __restrict__ b2,
                     const float* __restrict__ Wp, const float* __restrict__ bp,
                     float* __restrict__ out)
{
    // pool layout (time-multiplexed):
    //  select stage: qbuf u64[CAP] @0 (12K) | idxbuf int[CAP] @12288 (6K) |
    //                qmins f32[512] @18432 | pairmin f32[256] @20480
    //  MLP stage:    msg bf16[32][256] @0 (16K, XOR-swizzled rows)
    __shared__ __align__(16) char pool[21504];
    unsigned long long* qbuf = (unsigned long long*)pool;
    int*    idxbuf  = (int*)(pool + 12288);
    float*  qmins   = (float*)(pool + 18432);
    float*  pairmin = (float*)(pool + 20480);
    ushort* msg     = (ushort*)pool;

    __shared__ float rf[KNB][5];
    __shared__ int   sel[KNB];
    __shared__ float hb[H];
    __shared__ float feats[2 * H];
    __shared__ float p2[512];
    __shared__ float tau_sh;
    __shared__ int   cnt;

    const int s = blockIdx.x;
    const int t = threadIdx.x;
    const int lane = t & 63;
    const int w = t >> 6;

    const int sidx = supidx[s];
    const float4 sp = pos4[sidx];
    const float sx = sp.x, sy = sp.y, sz = sp.z;
    const float c0 = -2.f * sx, c1 = -2.f * sy, c2 = -2.f * sz;

    constexpr float L2_10000 = 13.287712379549449f;

    // ---- phase 0: supernode abs-pos embed -> feats[0..255]
    if (t < H) {
        float se = 0.f;
        if (t < 252) {
            int c  = t / 84;
            int rr = t - c * 84;
            int f  = (rr < 42) ? rr : rr - 42;
            float coord = (c == 0) ? sx : ((c == 1) ? sy : sz);
            float ang = coord * exp2f(-(float)f * (L2_10000 / 42.f));
            se = (rr < 42) ? __sinf(ang) : __cosf(ang);
        }
        feats[t] = se;
    }

    // ---- phase 1: sample 8192 points, per-thread min of q = |p|^2 - 2 s.p ----
    {
        float mn = INFINITY;
#pragma unroll
        for (int n = 0; n < 4; n++) {
            int i = n * 2048 + 4 * t;
            if (i + 3 < N) {
                float4 P0 = pos4[i], P1 = pos4[i + 1], P2 = pos4[i + 2], P3 = pos4[i + 3];
                float q0 = fmaf(P0.x, c0, fmaf(P0.y, c1, fmaf(P0.z, c2, P0.w)));
                float q1 = fmaf(P1.x, c0, fmaf(P1.y, c1, fmaf(P1.z, c2, P1.w)));
                float q2 = fmaf(P2.x, c0, fmaf(P2.y, c1, fmaf(P2.z, c2, P2.w)));
                float q3 = fmaf(P3.x, c0, fmaf(P3.y, c1, fmaf(P3.z, c2, P3.w)));
                mn = fminf(mn, fminf(fminf(q0, q1), fminf(q2, q3)));
            }
        }
        qmins[t] = mn;
    }
    __syncthreads();
    if (t < 256) pairmin[t] = fminf(qmins[2 * t], qmins[2 * t + 1]);
    if (t == 0) cnt = 0;
    __syncthreads();
    // rank-select the 32nd-smallest pair-min -> threshold (>= sample q-r32)
    if (t < 256) {
        float my = pairmin[t];
        int lt = 0, le = 0;
        for (int u = 0; u < 256; u += 4) {
            float4 v = *(const float4*)&pairmin[u];
            lt += (v.x < my) + (v.y < my) + (v.z < my) + (v.w < my);
            le += (v.x <= my) + (v.y <= my) + (v.z <= my) + (v.w <= my);
        }
        if (lt <= 31 && le > 31) tau_sh = my;   // tie-group writers write same value
    }
    __syncthreads();
    const float tau = tau_sh + 1e-3f;   // absorbs fp32 cancellation error of q-form

    // ---- phase 2: filter all N points; append survivors (exp ~200) ----
    {
        int base = 0;
        for (; base + 4 * TPB <= N; base += 4 * TPB) {
            int i = base + 4 * t;
            float4 P0 = pos4[i], P1 = pos4[i + 1], P2 = pos4[i + 2], P3 = pos4[i + 3];
            float q0 = fmaf(P0.x, c0, fmaf(P0.y, c1, fmaf(P0.z, c2, P0.w)));
            float q1 = fmaf(P1.x, c0, fmaf(P1.y, c1, fmaf(P1.z, c2, P1.w)));
            float q2 = fmaf(P2.x, c0, fmaf(P2.y, c1, fmaf(P2.z, c2, P2.w)));
            float q3 = fmaf(P3.x, c0, fmaf(P3.y, c1, fmaf(P3.z, c2, P3.w)));
            if (q0 <= tau) { int sl = atomicAdd(&cnt, 1); if (sl < CAP) idxbuf[sl] = i; }
            if (q1 <= tau) { int sl = atomicAdd(&cnt, 1); if (sl < CAP) idxbuf[sl] = i + 1; }
            if (q2 <= tau) { int sl = atomicAdd(&cnt, 1); if (sl < CAP) idxbuf[sl] = i + 2; }
            if (q3 <= tau) { int sl = atomicAdd(&cnt, 1); if (sl < CAP) idxbuf[sl] = i + 3; }
        }
        for (int i = base + t; i < N; i += TPB) {
            float4 P = pos4[i];
            float q = fmaf(P.x, c0, fmaf(P.y, c1, fmaf(P.z, c2, P.w)));
            if (q <= tau) { int sl = atomicAdd(&cnt, 1); if (sl < CAP) idxbuf[sl] = i; }
        }
    }
    __syncthreads();
    const int M = min(cnt, CAP);
    const int Mpad = (M + 1) & ~1;

    // ---- phase 3: exact d2 for survivors, pack (d2,idx), rank -> top-32 ----
    for (int u = t; u < Mpad; u += TPB) {
        unsigned long long pk = ~0ull;
        if (u < M) {
            int idx = idxbuf[u];
            float4 P = pos4[idx];
            float dx = sx - P.x, dy = sy - P.y, dz = sz - P.z;
            float d2 = dx * dx + dy * dy + dz * dz;     // same form as reference check
            pk = ((unsigned long long)__float_as_uint(d2) << 32) | (unsigned)idx;
        }
        qbuf[u] = pk;
    }
    __syncthreads();
    for (int u = t; u < M; u += TPB) {
        unsigned long long mine = qbuf[u];
        int rank = 0;
        for (int v = 0; v < Mpad; v += 2) {
            unsigned long long a = qbuf[v], b = qbuf[v + 1];
            rank += (a < mine) + (b < mine);
        }
        if (rank < KNB) sel[rank] = (int)(mine & 0xffffffffu);
    }
    __syncthreads();

    // ---- phase 4: rel features ----
    if (t < KNB) {
        int ni = sel[t];
        float4 P = pos4[ni];
        float rx = sx - P.x, ry = sy - P.y, rz = sz - P.z;
        float dd = sqrtf(rx * rx + ry * ry + rz * rz);
        rf[t][0] = rx; rf[t][1] = ry; rf[t][2] = rz; rf[t][3] = dd;
    }
    __syncthreads();

    // ---- phase 5: sincos embed -> msg[k][i] bf16, row-XOR swizzle ----
#pragma unroll
    for (int n = 0; n < 8; n++) {
        int item = t + n * TPB;
        int f = item & 31;
        int c = (item >> 5) & 3;
        int k = item >> 7;
        float ang = rf[k][c] * exp2f(-(float)f * (L2_10000 / 32.f));
        int swz = (k & 7) << 3;
        msg[((k << 8) | (c * 64 + f))      ^ swz] = f2bf(__sinf(ang));
        msg[((k << 8) | (c * 64 + 32 + f)) ^ swz] = f2bf(__cosf(ang));
    }
    __syncthreads();

    // ---- phase 6: MFMA GEMM1  h[j][k] = sum_i W1t[j][i]*msg[k][i] ----
    {
        const int lr = lane & 15;
        const int lg = lane >> 4;
        f32x4 acc00 = {0,0,0,0}, acc01 = {0,0,0,0};
        f32x4 acc10 = {0,0,0,0}, acc11 = {0,0,0,0};
#pragma unroll
        for (int kk = 0; kk < 8; kk++) {
            const int i0 = kk * 32 + lg * 8;
            bf16x8 a0 = *(const bf16x8*)(W1t + ((32 * w      + lr) << 8) + i0);
            bf16x8 a1 = *(const bf16x8*)(W1t + ((32 * w + 16 + lr) << 8) + i0);
            const int swz = (lr & 7) << 3;
            bf16x8 b0 = *(const bf16x8*)(msg + ((( lr       << 8) | i0) ^ swz));
            bf16x8 b1 = *(const bf16x8*)(msg + ((((lr + 16) << 8) | i0) ^ swz));
            acc00 = __builtin_amdgcn_mfma_f32_16x16x32_bf16(a0, b0, acc00, 0, 0, 0);
            acc01 = __builtin_amdgcn_mfma_f32_16x16x32_bf16(a0, b1, acc01, 0, 0, 0);
            acc10 = __builtin_amdgcn_mfma_f32_16x16x32_bf16(a1, b0, acc10, 0, 0, 0);
            acc11 = __builtin_amdgcn_mfma_f32_16x16x32_bf16(a1, b1, acc11, 0, 0, 0);
        }
        float part[8];
#pragma unroll
        for (int m = 0; m < 2; m++)
#pragma unroll
            for (int r = 0; r < 4; r++) {
                int j = 32 * w + 16 * m + 4 * lg + r;
                float bj = b1[j];
                float h0 = (m == 0 ? acc00[r] : acc10[r]) + bj;
                float h1 = (m == 0 ? acc01[r] : acc11[r]) + bj;
                part[m * 4 + r] = gelu_fast(h0) + gelu_fast(h1);
            }
#pragma unroll
        for (int off = 1; off < 16; off <<= 1)
#pragma unroll
            for (int u = 0; u < 8; u++)
                part[u] += __shfl_xor(part[u], off);
        if (lr == 0) {
#pragma unroll
            for (int u = 0; u < 8; u++) {
                int m = u >> 2, r = u & 3;
                hb[32 * w + 16 * m + 4 * lg + r] = part[u] * (1.0f / 32.0f);
            }
        }
    }
    __syncthreads();

    // ---- phase 7: GEMM2 matvec agg = hb @ W2 + b2 (2 threads/output) ----
    {
        const int j = t & 255, half = t >> 8;
        const int i0 = half * 128;
        float a[8];
#pragma unroll
        for (int u = 0; u < 8; u++) a[u] = 0.f;
        for (int st = 0; st < 16; st++) {
            int i = i0 + st * 8;
#pragma unroll
            for (int u = 0; u < 8; u++)
                a[u] += hb[i + u] * W2[(i + u) * H + j];
        }
        p2[t] = ((a[0] + a[1]) + (a[2] + a[3])) + ((a[4] + a[5]) + (a[6] + a[7]));
    }
    __syncthreads();
    if (t < 256) feats[H + t] = p2[t] + p2[256 + t] + b2[t];
    __syncthreads();

    // ---- phase 8: final projection out = feats @ Wp + bp (2 threads/output) ----
    {
        const int j = t & 255, half = t >> 8;
        const int i0 = half * 256;
        float o[8];
#pragma unroll
        for (int u = 0; u < 8; u++) o[u] = 0.f;
        for (int st = 0; st < 32; st++) {
            int i = i0 + st * 8;
#pragma unroll
            for (int u = 0; u < 8; u++)
                o[u] += feats[i + u] * Wp[(i + u) * H + j];
        }
        p2[t] = ((o[0] + o[1]) + (o[2] + o[3])) + ((o[4] + o[5]) + (o[6] + o[7]));
    }
    __syncthreads();
    if (t < 256) out[s * H + t] = p2[t] + p2[256 + t] + bp[t];
}

extern "C" void kernel_launch(void* const* d_in, const int* in_sizes, int n_in,
                              void* d_out, int out_size, void* d_ws, size_t ws_size,
                              hipStream_t stream) {
    const float* pos = (const float*)d_in[0];
    const int*   sup = (const int*)d_in[1];
    const float* W1  = (const float*)d_in[2];
    const float* b1  = (const float*)d_in[3];
    const float* W2  = (const float*)d_in[4];
    const float* b2  = (const float*)d_in[5];
    const float* Wp  = (const float*)d_in[6];
    const float* bp  = (const float*)d_in[7];

    const int N = in_sizes[0] / 3;
    const int S = in_sizes[1];
    float* out = (float*)d_out;

    ushort* W1t  = (ushort*)d_ws;                       // 128 KB
    float4* pos4 = (float4*)((char*)d_ws + 131072);     // 800 KB

    const int prep_blocks = 64 + (N + 255) / 256;
    prep<<<prep_blocks, 256, 0, stream>>>(W1, pos, N, W1t, pos4);
    supernode_fused<<<S, TPB, 0, stream>>>(pos4, N, sup, W1t, b1, W2, b2, Wp, bp, out);
}